// Round 9
// baseline (96.817 us; speedup 1.0000x reference)
//
#include <hip/hip_runtime.h>
#include <math.h>

// HMM marginal via bf16 MFMA, T held in REGISTERS (loop-invariant).
//   beta = ones; for t = 11..1: beta = (emit[tok_t] * beta) @ T   (per batch row)
//   out[b] = -log( sum_k emit[tok_0][k] * pi[k] * beta0[k] )
// Z=256, X=64, S=12, B=8192.
//
// chain_kernel: 256 blocks x 256 thr (4 waves, 1/SIMD), 1 block/CU.
//   T: fragment-packed bf16 in 128 VGPRs per thread (loaded once from L2).
//   beta: LDS, double-buffered, 32 rows x 512B, XOR-swizzled byte^=(row&7)<<4.
//   Per step: A-frag = beta (LDS) * emit-gather (L2) fused at load -> 64 MFMA
//   -> writeback to other buffer -> ONE barrier.

#define ZD 256
#define XD 64
#define SL 12
#define BM 32

typedef short bf16x8 __attribute__((ext_vector_type(8)));
typedef float f32x4  __attribute__((ext_vector_type(4)));

__device__ __forceinline__ ushort f2bf(float f) {
    uint u = __float_as_uint(f);
    return (ushort)((u + 0x7FFFu + ((u >> 16) & 1u)) >> 16);   // RNE
}
__device__ __forceinline__ float bflo(uint w) { return __uint_as_float(w << 16); }
__device__ __forceinline__ float bfhi(uint w) { return __uint_as_float(w & 0xFFFF0000u); }
__device__ __forceinline__ uint pk_bf16(float lo, float hi) {
    uint r;
    asm("v_cvt_pk_bf16_f32 %0, %1, %2" : "=v"(r) : "v"(lo), "v"(hi));
    return r;
}
__device__ __forceinline__ int bswz(int row, int kbyte) {   // swizzled byte offset in a beta buffer
    return row * 512 + (kbyte ^ ((row & 7) << 4));
}
__device__ __forceinline__ bf16x8 bmul(bf16x8 a, bf16x8 b) {   // elementwise bf16 mul (f32 math, RNE pack)
    union { bf16x8 v; uint4 u; } ua, ub, r;
    ua.v = a; ub.v = b;
    r.u.x = pk_bf16(bflo(ua.u.x) * bflo(ub.u.x), bfhi(ua.u.x) * bfhi(ub.u.x));
    r.u.y = pk_bf16(bflo(ua.u.y) * bflo(ub.u.y), bfhi(ua.u.y) * bfhi(ub.u.y));
    r.u.z = pk_bf16(bflo(ua.u.z) * bflo(ub.u.z), bfhi(ua.u.z) * bfhi(ub.u.z));
    r.u.w = pk_bf16(bflo(ua.u.w) * bflo(ub.u.w), bfhi(ua.u.w) * bfhi(ub.u.w));
    return r.v;
}

// ---------------- prep: softmaxes + fragment packing ----------------
// grid = 258. bid<256: T column softmax (col=bid, thread=row), written
// fragment-packed: Tp[((ks*16+ct)*64 + l)*8 + j] for lane l, B-frag (ct,ks).
// bid==256: emit col softmax -> bf16 row-major [x][z]. bid==257: pi -> f32.
__global__ __launch_bounds__(256) void prep_kernel(
    const float* __restrict__ Tl, const float* __restrict__ pil,
    const float* __restrict__ El, ushort* __restrict__ Tp,
    ushort* __restrict__ emit_g, float* __restrict__ pi_g)
{
    __shared__ float wsum[4];
    const int tid = threadIdx.x;
    const int bid = blockIdx.x;

    if (bid < ZD) {
        const int n = bid, k = tid;
        float e = __expf(Tl[k * ZD + n]);
        float v = e;
        #pragma unroll
        for (int o = 32; o > 0; o >>= 1) v += __shfl_down(v, o);
        if ((tid & 63) == 0) wsum[tid >> 6] = v;
        __syncthreads();
        float inv = 1.f / (wsum[0] + wsum[1] + wsum[2] + wsum[3]);
        // B-frag packing: lane holds (n = ct*16+ll), 8 contiguous k at (lh*8)
        int ks = k >> 5, lh = (k >> 3) & 3, j7 = k & 7;
        int ct = n >> 4, ll = n & 15;
        Tp[(((ks * 16 + ct) * 64) + lh * 16 + ll) * 8 + j7] = f2bf(e * inv);
    } else if (bid == ZD) {
        const int z = tid;
        float s = 0.f;
        #pragma unroll 16
        for (int x = 0; x < XD; ++x) s += __expf(El[x * ZD + z]);
        float inv = 1.f / s;
        #pragma unroll 8
        for (int x = 0; x < XD; ++x)
            emit_g[x * ZD + z] = f2bf(__expf(El[x * ZD + z]) * inv);
    } else {
        float e = __expf(pil[tid]);
        float v = e;
        #pragma unroll
        for (int o = 32; o > 0; o >>= 1) v += __shfl_down(v, o);
        if ((tid & 63) == 0) wsum[tid >> 6] = v;
        __syncthreads();
        pi_g[tid] = e / (wsum[0] + wsum[1] + wsum[2] + wsum[3]);
    }
}

// one recursion step: read beta from rbuf (unless FIRST: beta==1), fold emit,
// MFMA against register-resident T, write new beta to wbuf. NO internal sync.
template<bool FIRST>
__device__ __forceinline__ void hmm_step(
    const char* rbuf, char* wbuf, const int* tokrow, const char* emitb,
    const bf16x8 (&treg)[4][8], int ll, int lh, int w)
{
    f32x4 acc[2][4];
    #pragma unroll
    for (int rt = 0; rt < 2; ++rt)
        #pragma unroll
        for (int cj = 0; cj < 4; ++cj) acc[rt][cj] = (f32x4)0.f;

    #pragma unroll
    for (int ks = 0; ks < 8; ++ks) {
        bf16x8 af[2];
        #pragma unroll
        for (int rt = 0; rt < 2; ++rt) {
            const int r  = rt * 16 + ll;
            const int kb = (ks * 32 + lh * 8) * 2;            // byte offset of 8 contiguous k
            const int tok = tokrow[r];
            bf16x8 ev = *(const bf16x8*)(emitb + tok * 512 + kb);   // L2-hot gather
            if (FIRST) {
                af[rt] = ev;                                   // beta == 1
            } else {
                bf16x8 bb = *(const bf16x8*)(rbuf + bswz(r, kb));
                af[rt] = bmul(bb, ev);
            }
        }
        #pragma unroll
        for (int rt = 0; rt < 2; ++rt)
            #pragma unroll
            for (int cj = 0; cj < 4; ++cj)
                acc[rt][cj] = __builtin_amdgcn_mfma_f32_16x16x32_bf16(
                    af[rt], treg[cj][ks], acc[rt][cj], 0, 0, 0);
    }

    // writeback: D col = lane&15 (state), row = (lane>>4)*4+reg (batch row)
    #pragma unroll
    for (int rt = 0; rt < 2; ++rt)
        #pragma unroll
        for (int cj = 0; cj < 4; ++cj) {
            const int col = (w * 4 + cj) * 16 + ll;
            const int r0  = rt * 16 + lh * 4;
            uint w01 = pk_bf16(acc[rt][cj][0], acc[rt][cj][1]);
            uint w23 = pk_bf16(acc[rt][cj][2], acc[rt][cj][3]);
            *(ushort*)(wbuf + bswz(r0 + 0, col * 2)) = (ushort)w01;
            *(ushort*)(wbuf + bswz(r0 + 1, col * 2)) = (ushort)(w01 >> 16);
            *(ushort*)(wbuf + bswz(r0 + 2, col * 2)) = (ushort)w23;
            *(ushort*)(wbuf + bswz(r0 + 3, col * 2)) = (ushort)(w23 >> 16);
        }
}

// ---------------- chain ----------------
__global__ __launch_bounds__(256, 1) void chain_kernel(
    const int* __restrict__ tokens, const ushort* __restrict__ Tp_g,
    const ushort* __restrict__ emit_g, const float* __restrict__ pi_g,
    float* __restrict__ out, int B)
{
    __shared__ __align__(16) char beta[2][BM * 512];   // 32 KB double buffer
    __shared__ int   toks[SL][BM];                     // 1.5 KB
    __shared__ float red[8][BM];                       // 1 KB

    const int tid  = threadIdx.x;
    const int row0 = blockIdx.x * BM;
    const int l  = tid & 63;
    const int w  = tid >> 6;
    const int ll = l & 15;
    const int lh = l >> 4;
    const char* emitb = (const char*)emit_g;

    // T fragments -> 128 VGPRs (loop-invariant; coalesced b128 loads from L2)
    bf16x8 treg[4][8];
    {
        const bf16x8* TG = (const bf16x8*)Tp_g;
        #pragma unroll
        for (int ks = 0; ks < 8; ++ks)
            #pragma unroll
            for (int cj = 0; cj < 4; ++cj)
                treg[cj][ks] = TG[(ks * 16 + (w * 4 + cj)) * 64 + l];
    }

    for (int i = tid; i < SL * BM; i += 256)
        toks[i >> 5][i & 31] = tokens[(i >> 5) * B + row0 + (i & 31)];
    __syncthreads();

    // t = 11 (beta == 1) writes beta[0]; then alternate. Final result in beta[0].
    hmm_step<true>(beta[1], beta[0], &toks[SL - 1][0], emitb, treg, ll, lh, w);
    __syncthreads();
    int cur = 0;                       // buffer holding newest beta
    for (int t = SL - 2; t >= 1; --t) {
        hmm_step<false>(beta[cur], beta[cur ^ 1], &toks[t][0], emitb, treg, ll, lh, w);
        __syncthreads();
        cur ^= 1;
    }

    // ---- final: out[r] = -log( sum_k emit[tok0][k] * pi[k] * beta0[k][r] )
    {
        const char* fb = beta[cur];
        const int r = tid & 31, q = tid >> 5;   // 8 partials per row
        const int tok0 = toks[0][r];
        float s = 0.f;
        #pragma unroll
        for (int i = 0; i < 4; ++i) {
            int k0 = q * 32 + i * 8;
            int kb = k0 * 2;
            uint4 bb = *(const uint4*)(fb + bswz(r, kb));
            uint4 ee = *(const uint4*)(emitb + tok0 * 512 + kb);
            const float4* pf = (const float4*)(pi_g + k0);
            float4 pA = pf[0], pB = pf[1];
            s += bflo(bb.x) * bflo(ee.x) * pA.x + bfhi(bb.x) * bfhi(ee.x) * pA.y;
            s += bflo(bb.y) * bflo(ee.y) * pA.z + bfhi(bb.y) * bfhi(ee.y) * pA.w;
            s += bflo(bb.z) * bflo(ee.z) * pB.x + bfhi(bb.z) * bfhi(ee.z) * pB.y;
            s += bflo(bb.w) * bflo(ee.w) * pB.z + bfhi(bb.w) * bfhi(ee.w) * pB.w;
        }
        red[q][r] = s;
        __syncthreads();
        if (tid < BM) {
            float tot = 0.f;
            #pragma unroll
            for (int q2 = 0; q2 < 8; ++q2) tot += red[q2][tid];
            out[row0 + tid] = -__logf(tot);
        }
    }
}

extern "C" void kernel_launch(void* const* d_in, const int* in_sizes, int n_in,
                              void* d_out, int out_size, void* d_ws, size_t ws_size,
                              hipStream_t stream)
{
    (void)n_in; (void)out_size; (void)ws_size;
    const int*   tokens = (const int*)d_in[0];
    const float* Tl     = (const float*)d_in[1];
    const float* pil    = (const float*)d_in[2];
    const float* El     = (const float*)d_in[3];
    float*       outp   = (float*)d_out;

    const int B = in_sizes[0] / SL;

    char*   wsb    = (char*)d_ws;
    ushort* Tp     = (ushort*)wsb;                       // 128KB packed T
    ushort* emit_g = (ushort*)(wsb + 131072);            // 32KB bf16 [64][256]
    float*  pi_g   = (float*)(wsb + 131072 + 32768);     // 1KB f32

    prep_kernel<<<ZD + 2, 256, 0, stream>>>(Tl, pil, El, Tp, emit_g, pi_g);
    chain_kernel<<<B / BM, 256, 0, stream>>>(tokens, Tp, emit_g, pi_g, outp, B);
}

// Round 12
// 91.621 us; speedup vs baseline: 1.0567x; 1.0567x over previous
//
#include <hip/hip_runtime.h>
#include <math.h>

// HMM marginal via bf16 MFMA (round-7 verified kernel: 92.4us, absmax 0.25).
//   beta = ones; for t = 11..1: beta = (emit[tok_t] * beta) @ T   (per batch row)
//   out[b] = -log( sum_z emit[tok_0][z] * pi[z] * beta0[z] )
// Z=256, X=64, S=12, B=8192.
//
// chain_kernel: 256 blocks x 256 thr (4 waves), 1 block/CU.
//   LDS: T (bf16, fragment-packed, 128KB, resident all 11 steps)
//        beta (bf16, 32 rows x 512B, XOR-swizzled byte^=(row&7)<<4)
//   Per step: A-prep (beta *= emit-gather, in place) -> 64 MFMA/wave -> writeback.
// Measured context: harness poison fills (~80us, 268MB x2 at ~6.6TB/s) dominate
// the timed window; prep+chain are ~12us of the 92.4.

#define ZD 256
#define XD 64
#define SL 12
#define BM 32

typedef short bf16x8 __attribute__((ext_vector_type(8)));
typedef float f32x4  __attribute__((ext_vector_type(4)));

#define TP_BYTES   131072              // 256*256 bf16
#define BETA_OFF   131072              // 32 * 512B = 16KB
#define TOK_OFF    147456              // 12*32*4
#define RED_OFF    148992              // 256*4
#define SMEM_BYTES 150016

__device__ __forceinline__ ushort f2bf(float f) {
    uint u = __float_as_uint(f);
    return (ushort)((u + 0x7FFFu + ((u >> 16) & 1u)) >> 16);   // RNE
}
__device__ __forceinline__ float bflo(uint w) { return __uint_as_float(w << 16); }
__device__ __forceinline__ float bfhi(uint w) { return __uint_as_float(w & 0xFFFF0000u); }
__device__ __forceinline__ uint pk_bf16(float lo, float hi) {
    uint r;
    asm("v_cvt_pk_bf16_f32 %0, %1, %2" : "=v"(r) : "v"(lo), "v"(hi));
    return r;
}
__device__ __forceinline__ int bswz(int row, int kbyte) {     // swizzled byte offset into beta
    return BETA_OFF + row * 512 + (kbyte ^ ((row & 7) << 4));
}

// ---------------- prep: softmaxes + fragment packing ----------------
// grid = 258. bid<256: T column softmax (col=bid, thread=row), written
// fragment-packed so chain's B-frag load is ((ks*16+ct)*64 + lane)*8 + j.
// bid==256: emit col softmax -> bf16 row-major [x][z]. bid==257: pi -> f32.
__global__ __launch_bounds__(256) void prep_kernel(
    const float* __restrict__ Tl, const float* __restrict__ pil,
    const float* __restrict__ El, ushort* __restrict__ Tp,
    ushort* __restrict__ emit_g, float* __restrict__ pi_g)
{
    __shared__ float wsum[4];
    const int tid = threadIdx.x;
    const int bid = blockIdx.x;

    if (bid < ZD) {
        const int n = bid, k = tid;
        float e = __expf(Tl[k * ZD + n]);
        float v = e;
        #pragma unroll
        for (int o = 32; o > 0; o >>= 1) v += __shfl_down(v, o);
        if ((tid & 63) == 0) wsum[tid >> 6] = v;
        __syncthreads();
        float inv = 1.f / (wsum[0] + wsum[1] + wsum[2] + wsum[3]);
        // B-frag packing: lane holds (n = ct*16+ll), 8 contiguous k at (lh*8)
        int ks = k >> 5, lh = (k >> 3) & 3, j7 = k & 7;
        int ct = n >> 4, ll = n & 15;
        Tp[(((ks * 16 + ct) * 64) + lh * 16 + ll) * 8 + j7] = f2bf(e * inv);
    } else if (bid == ZD) {
        const int z = tid;
        float s = 0.f;
        #pragma unroll 8
        for (int x = 0; x < XD; ++x) s += __expf(El[x * ZD + z]);
        float inv = 1.f / s;
        for (int x = 0; x < XD; ++x)
            emit_g[x * ZD + z] = f2bf(__expf(El[x * ZD + z]) * inv);
    } else {
        float e = __expf(pil[tid]);
        float v = e;
        #pragma unroll
        for (int o = 32; o > 0; o >>= 1) v += __shfl_down(v, o);
        if ((tid & 63) == 0) wsum[tid >> 6] = v;
        __syncthreads();
        pi_g[tid] = e / (wsum[0] + wsum[1] + wsum[2] + wsum[3]);
    }
}

// ---------------- chain ----------------
__global__ __launch_bounds__(256) void chain_kernel(
    const int* __restrict__ tokens, const ushort* __restrict__ Tp_g,
    const ushort* __restrict__ emit_g, const float* __restrict__ pi_g,
    float* __restrict__ out, int B)
{
    extern __shared__ __align__(16) char smem[];
    const int tid  = threadIdx.x;
    const int row0 = blockIdx.x * BM;

    // stage packed T: 128KB, linear (conflict-free both sides)
    {
        const uint4* src = (const uint4*)Tp_g;
        uint4* dst = (uint4*)smem;
        #pragma unroll 8
        for (int i = 0; i < 32; ++i) dst[tid + 256 * i] = src[tid + 256 * i];
    }
    int* toks = (int*)(smem + TOK_OFF);
    for (int i = tid; i < SL * BM; i += 256)
        toks[i] = tokens[(i >> 5) * B + row0 + (i & 31)];
    // beta = 1.0 (bf16 0x3F80)
    {
        uint4 one; one.x = one.y = one.z = one.w = 0x3F803F80u;
        #pragma unroll
        for (int c = 0; c < 4; ++c) {
            int g = tid + 256 * c;
            int r = g >> 5, kb = (g & 31) << 4;
            *(uint4*)(smem + bswz(r, kb)) = one;
        }
    }
    __syncthreads();

    const int l  = tid & 63;
    const int w  = tid >> 6;
    const int ll = l & 15;
    const int lh = l >> 4;
    const char* emitb = (const char*)emit_g;

    for (int t = SL - 1; t >= 1; --t) {
        // ---- A-prep: beta *= emit[tok_t][.] (in place; thread-exclusive chunks)
        #pragma unroll
        for (int c = 0; c < 4; ++c) {
            int g = tid + 256 * c;
            int r = g >> 5, kb = (g & 31) << 4;       // kbyte = k0*2
            int tok = toks[t * BM + r];
            char* bp = smem + bswz(r, kb);
            uint4 bb = *(uint4*)bp;
            uint4 ee = *(const uint4*)(emitb + tok * 512 + kb);
            uint4 oo;
            oo.x = pk_bf16(bflo(bb.x) * bflo(ee.x), bfhi(bb.x) * bfhi(ee.x));
            oo.y = pk_bf16(bflo(bb.y) * bflo(ee.y), bfhi(bb.y) * bfhi(ee.y));
            oo.z = pk_bf16(bflo(bb.z) * bflo(ee.z), bfhi(bb.z) * bfhi(ee.z));
            oo.w = pk_bf16(bflo(bb.w) * bflo(ee.w), bfhi(bb.w) * bfhi(ee.w));
            *(uint4*)bp = oo;
        }
        __syncthreads();

        // ---- MFMA: beta_new = A @ T. Wave owns col-tiles 4w..4w+3, rows 0..31.
        f32x4 acc[2][4];
        #pragma unroll
        for (int rt = 0; rt < 2; ++rt)
            #pragma unroll
            for (int cj = 0; cj < 4; ++cj) acc[rt][cj] = (f32x4)0.f;

        #pragma unroll
        for (int ks = 0; ks < 8; ++ks) {
            bf16x8 af[2], bfr[4];
            #pragma unroll
            for (int rt = 0; rt < 2; ++rt) {
                int r  = rt * 16 + ll;                 // A row = lane&15
                int kb = (ks * 32 + lh * 8) * 2;       // 8 contiguous k at (lane>>4)*8
                af[rt] = *(const bf16x8*)(smem + bswz(r, kb));
            }
            #pragma unroll
            for (int cj = 0; cj < 4; ++cj) {
                int ct = w * 4 + cj;
                bfr[cj] = *(const bf16x8*)(smem + ((ks * 16 + ct) * 64 + l) * 16);
            }
            #pragma unroll
            for (int rt = 0; rt < 2; ++rt)
                #pragma unroll
                for (int cj = 0; cj < 4; ++cj)
                    acc[rt][cj] = __builtin_amdgcn_mfma_f32_16x16x32_bf16(
                        af[rt], bfr[cj], acc[rt][cj], 0, 0, 0);
        }
        __syncthreads();   // all A-frag reads complete before overwrite

        // ---- writeback: D row = rt*16 + lh*4 + reg, col = (w*4+cj)*16 + ll
        #pragma unroll
        for (int rt = 0; rt < 2; ++rt)
            #pragma unroll
            for (int cj = 0; cj < 4; ++cj) {
                int col = (w * 4 + cj) * 16 + ll;
                int r0  = rt * 16 + lh * 4;
                uint w01 = pk_bf16(acc[rt][cj][0], acc[rt][cj][1]);
                uint w23 = pk_bf16(acc[rt][cj][2], acc[rt][cj][3]);
                *(ushort*)(smem + bswz(r0 + 0, col * 2)) = (ushort)w01;
                *(ushort*)(smem + bswz(r0 + 1, col * 2)) = (ushort)(w01 >> 16);
                *(ushort*)(smem + bswz(r0 + 2, col * 2)) = (ushort)w23;
                *(ushort*)(smem + bswz(r0 + 3, col * 2)) = (ushort)(w23 >> 16);
            }
        __syncthreads();
    }

    // ---- final: out[r] = -log( sum_k e0[k]*pi[k]*beta0[k][r] )
    {
        float* red = (float*)(smem + RED_OFF);
        const int r = tid & 31, q = tid >> 5;
        const int tok0 = toks[r];
        float s = 0.f;
        #pragma unroll
        for (int i = 0; i < 4; ++i) {
            int k0 = q * 32 + i * 8;
            int kb = k0 * 2;
            uint4 bb = *(const uint4*)(smem + bswz(r, kb));
            uint4 ee = *(const uint4*)(emitb + tok0 * 512 + kb);
            const float4* pf = (const float4*)(pi_g + k0);
            float4 pA = pf[0], pB = pf[1];
            s += bflo(bb.x) * bflo(ee.x) * pA.x + bfhi(bb.x) * bfhi(ee.x) * pA.y;
            s += bflo(bb.y) * bflo(ee.y) * pA.z + bfhi(bb.y) * bfhi(ee.y) * pA.w;
            s += bflo(bb.z) * bflo(ee.z) * pB.x + bfhi(bb.z) * bfhi(ee.z) * pB.y;
            s += bflo(bb.w) * bflo(ee.w) * pB.z + bfhi(bb.w) * bfhi(ee.w) * pB.w;
        }
        red[tid] = s;
        __syncthreads();
        if (tid < BM) {
            float tot = 0.f;
            #pragma unroll
            for (int q2 = 0; q2 < 8; ++q2) tot += red[q2 * 32 + tid];
            out[row0 + tid] = -__logf(tot);
        }
    }
}

extern "C" void kernel_launch(void* const* d_in, const int* in_sizes, int n_in,
                              void* d_out, int out_size, void* d_ws, size_t ws_size,
                              hipStream_t stream)
{
    (void)n_in; (void)out_size; (void)ws_size;
    const int*   tokens = (const int*)d_in[0];
    const float* Tl     = (const float*)d_in[1];
    const float* pil    = (const float*)d_in[2];
    const float* El     = (const float*)d_in[3];
    float*       outp   = (float*)d_out;

    const int B = in_sizes[0] / SL;

    char*   wsb    = (char*)d_ws;
    ushort* Tp     = (ushort*)wsb;                       // 128KB packed T
    ushort* emit_g = (ushort*)(wsb + TP_BYTES);          // 32KB bf16 [64][256]
    float*  pi_g   = (float*)(wsb + TP_BYTES + 32768);   // 1KB f32

    hipFuncSetAttribute((const void*)chain_kernel,
                        hipFuncAttributeMaxDynamicSharedMemorySize, SMEM_BYTES);

    prep_kernel<<<ZD + 2, 256, 0, stream>>>(Tl, pil, El, Tp, emit_g, pi_g);
    chain_kernel<<<B / BM, 256, SMEM_BYTES, stream>>>(tokens, Tp, emit_g, pi_g, outp, B);
}